// Round 18
// baseline (799.829 us; speedup 1.0000x reference)
//
#include <hip/hip_runtime.h>
#include <hip/hip_bf16.h>
#include <hip/hip_fp16.h>

// Problem constants: N=100000, F=128, O=128, S=4, B=2, E=3200000
#define NN 100000
#define FF 128
#define OO 128
#define SS 4
#define BBASES 2
#define EE 3200000
#define TOTE (SS * EE)   // 12.8M edges total
#define BROWS 32         // rows per fine bucket
#define NBUK 3125        // 100000/32 exactly
#define NCOARSE 98       // row>>10 buckets (1024 rows each)
#define SCAP 4608        // LDS stage cap; lambda=4096, +8 sigma
#define RBLOCKS 2048     // R18: 512->2048 (2 -> 8 blocks/CU: occupancy fix)
#define P2PARTS 32       // R18: 8->32

typedef unsigned int uintx2 __attribute__((ext_vector_type(2)));
typedef float floatx4 __attribute__((ext_vector_type(4)));
typedef _Float16 f16x8 __attribute__((ext_vector_type(8)));
typedef float f32x4 __attribute__((ext_vector_type(4)));

static __device__ __forceinline__ float2 h2_to_f2(unsigned int u) {
  __half2 h = *reinterpret_cast<__half2*>(&u);
  return __half22float2(h);
}

// ===========================================================================
// out[n] = tanh( G0[n] @ W0 + G1[n] @ W1 ),
//   G_b[n] = sum_{edges e->n} (val_e * Wc[s_e,b]) * feat[col_e]
// R18 = R17 + prep-occupancy fix (RBLOCKS 2048, P2PARTS 32) + 2x-unrolled
// pull loop (dual accumulators -> 2 independent gathers in flight per iter).
// Record: bits[16:0]=col, [21:17]=row&31, [26:22]=(row>>5)&31.
// rec.y = half2(val*w0, val*w1).
// ===========================================================================

// ---- fine-bucket histogram (LDS-staged) -----------------------------------
__global__ __launch_bounds__(256) void histB_kernel(
    const int* __restrict__ rows, unsigned int* __restrict__ bhist) {
  __shared__ unsigned int lh[NBUK];
  for (int i = threadIdx.x; i < NBUK; i += 256) lh[i] = 0;
  __syncthreads();
  const int stride = gridDim.x * 256;
  for (int i = blockIdx.x * 256 + threadIdx.x; i < TOTE; i += stride)
    atomicAdd(&lh[((unsigned)rows[i]) >> 5], 1u);
  __syncthreads();
  for (int i = threadIdx.x; i < NBUK; i += 256) {
    unsigned int c = lh[i];
    if (c) atomicAdd(&bhist[i], c);
  }
}

// ---- scan: fine bstart + fine cursors + coarse cursors --------------------
__global__ __launch_bounds__(256) void scanB_kernel(
    const unsigned int* __restrict__ bhist, unsigned int* __restrict__ bstart,
    unsigned int* __restrict__ fcur, unsigned int* __restrict__ ccur) {
  __shared__ unsigned int sums[256];
  const int C = (NBUK + 255) / 256;  // 14
  const int t = threadIdx.x;
  unsigned int s = 0;
  for (int j = 0; j < C; ++j) {
    int i = t * C + j;
    if (i < NBUK) s += bhist[i];
  }
  sums[t] = s;
  __syncthreads();
  for (int off = 1; off < 256; off <<= 1) {
    unsigned int v = (t >= off) ? sums[t - off] : 0u;
    __syncthreads();
    sums[t] += v;
    __syncthreads();
  }
  unsigned int base = (t == 0) ? 0u : sums[t - 1];
  for (int j = 0; j < C; ++j) {
    int i = t * C + j;
    if (i < NBUK) {
      unsigned int h = bhist[i];
      bstart[i] = base;
      fcur[i] = base;
      base += h;
    }
  }
  if (t == 255) bstart[NBUK] = base;  // == TOTE
  __syncthreads();
  if (t < NCOARSE) ccur[t] = bstart[t * 32];
}

// ---- P1: coarse partition (98 buckets), Wc fold, fine bits in record ------
__global__ __launch_bounds__(256) void part1_kernel(
    const int* __restrict__ rows, const int* __restrict__ cols,
    const float* __restrict__ vals, const float* __restrict__ Wc,
    unsigned int* __restrict__ ccur, uintx2* __restrict__ recsA) {
  __shared__ unsigned int lcnt[NCOARSE];
  __shared__ unsigned int lbase[NCOARSE];
  const float c00 = Wc[0], c01 = Wc[1], c10 = Wc[2], c11 = Wc[3];
  const float c20 = Wc[4], c21 = Wc[5], c30 = Wc[6], c31 = Wc[7];
  const int C = (TOTE + RBLOCKS - 1) / RBLOCKS;  // 6250
  const int start = blockIdx.x * C;
  const int end = min(start + C, TOTE);
  const int tid = threadIdx.x;
  if (tid < NCOARSE) lcnt[tid] = 0;
  __syncthreads();
  for (int i = start + tid; i < end; i += 256)
    atomicAdd(&lcnt[((unsigned)rows[i]) >> 10], 1u);
  __syncthreads();
  if (tid < NCOARSE) {
    unsigned int c = lcnt[tid];
    lbase[tid] = c ? atomicAdd(&ccur[tid], c) : 0u;
    lcnt[tid] = 0;
  }
  __syncthreads();
  for (int i = start + tid; i < end; i += 256) {
    unsigned int r = (unsigned)rows[i];
    int bk = r >> 10;
    unsigned int p = lbase[bk] + atomicAdd(&lcnt[bk], 1u);
    unsigned int s = (unsigned)(i / EE);
    float val = vals[i];
    float w0 = (s == 0) ? c00 : (s == 1) ? c10 : (s == 2) ? c20 : c30;
    float w1 = (s == 0) ? c01 : (s == 1) ? c11 : (s == 2) ? c21 : c31;
    __half2 hv = __floats2half2_rn(val * w0, val * w1);
    uintx2 rec;
    rec.x = ((unsigned)cols[i]) | ((r & 31u) << 17) | (((r >> 5) & 31u) << 22);
    rec.y = *reinterpret_cast<unsigned int*>(&hv);
    recsA[p] = rec;  // CACHED: L2 write-combines the 8B scatter
  }
}

// ---- P2: fine partition within each coarse region -------------------------
__global__ __launch_bounds__(256) void part2_kernel(
    const uintx2* __restrict__ recsA, const unsigned int* __restrict__ bstart,
    unsigned int* __restrict__ fcur, uintx2* __restrict__ recsB) {
  __shared__ unsigned int lcnt[32];
  __shared__ unsigned int lbase[32];
  const int c = blockIdx.x / P2PARTS;   // coarse bucket
  const int p = blockIdx.x % P2PARTS;
  const int f0 = c * 32;
  const int f1 = min(f0 + 32, NBUK);
  const unsigned int beg = bstart[f0];
  const unsigned int endc = bstart[f1];
  const unsigned int len = endc - beg;
  const unsigned int chunk = (len + P2PARTS - 1) / P2PARTS;
  const unsigned int s0 = beg + (unsigned)p * chunk;
  const unsigned int s1 = min(s0 + chunk, endc);
  const int tid = threadIdx.x;
  if (tid < 32) lcnt[tid] = 0;
  __syncthreads();
  for (unsigned int i = s0 + tid; i < s1; i += 256)
    atomicAdd(&lcnt[(recsA[i].x >> 22) & 31u], 1u);
  __syncthreads();
  if (tid < 32) {
    unsigned int cnt = lcnt[tid];
    lbase[tid] = (cnt && f0 + tid < NBUK) ? atomicAdd(&fcur[f0 + tid], cnt) : 0u;
    lcnt[tid] = 0;
  }
  __syncthreads();
  for (unsigned int i = s0 + tid; i < s1; i += 256) {
    uintx2 r = recsA[i];  // L2-hot second read
    unsigned int j = (r.x >> 22) & 31u;
    unsigned int pos = lbase[j] + atomicAdd(&lcnt[j], 1u);
    recsB[pos] = r;  // CACHED scatter
  }
}

// ---- Tier B: single-pass fine partition, 1024 threads ---------------------
#define RBLOCKSB 256
__global__ __launch_bounds__(1024) void partitionB_kernel(
    const int* __restrict__ rows, const int* __restrict__ cols,
    const float* __restrict__ vals, const float* __restrict__ Wc,
    unsigned int* __restrict__ fcur, uintx2* __restrict__ recs) {
  __shared__ unsigned int lcnt[NBUK];
  __shared__ unsigned int lbase[NBUK];
  const float c00 = Wc[0], c01 = Wc[1], c10 = Wc[2], c11 = Wc[3];
  const float c20 = Wc[4], c21 = Wc[5], c30 = Wc[6], c31 = Wc[7];
  const int C = (TOTE + RBLOCKSB - 1) / RBLOCKSB;  // 50000
  const int start = blockIdx.x * C;
  const int end = min(start + C, TOTE);
  const int tid = threadIdx.x;
  for (int i = tid; i < NBUK; i += 1024) lcnt[i] = 0;
  __syncthreads();
  for (int i = start + tid; i < end; i += 1024)
    atomicAdd(&lcnt[((unsigned)rows[i]) >> 5], 1u);
  __syncthreads();
  for (int i = tid; i < NBUK; i += 1024) {
    unsigned int c = lcnt[i];
    if (c) lbase[i] = atomicAdd(&fcur[i], c);
    lcnt[i] = 0;
  }
  __syncthreads();
  for (int i = start + tid; i < end; i += 1024) {
    unsigned int r = (unsigned)rows[i];
    int bk = r >> 5;
    unsigned int p = lbase[bk] + atomicAdd(&lcnt[bk], 1u);
    unsigned int s = (unsigned)(i / EE);
    float val = vals[i];
    float w0 = (s == 0) ? c00 : (s == 1) ? c10 : (s == 2) ? c20 : c30;
    float w1 = (s == 0) ? c01 : (s == 1) ? c11 : (s == 2) ? c21 : c31;
    __half2 hv = __floats2half2_rn(val * w0, val * w1);
    uintx2 rec;
    rec.x = ((unsigned)cols[i]) | ((r & 31u) << 17) | (((r >> 5) & 31u) << 22);
    rec.y = *reinterpret_cast<unsigned int*>(&hv);
    recs[p] = rec;  // CACHED scatter
  }
}

// ---- fp16 cast of feat: fb[i] packs elements 2i,2i+1 as half2 (RNE) -------
__global__ __launch_bounds__(256) void cast_kernel(const float* __restrict__ f,
                                                   unsigned int* __restrict__ fb) {
  int i = blockIdx.x * 256 + threadIdx.x;  // over N*F/2 = 6.4M pairs
  float2 a = reinterpret_cast<const float2*>(f)[i];
  __half2 h = __floats2half2_rn(a.x, a.y);
  fb[i] = *reinterpret_cast<unsigned int*>(&h);
}

// ---- fp16 transpose of W: Wt[o][k] = Wcat[k][o], [128][256] ---------------
__global__ __launch_bounds__(256) void castW_kernel(const float* __restrict__ W,
                                                    _Float16* __restrict__ Wt) {
  int i = blockIdx.x * 256 + threadIdx.x;  // over 2*FF*OO = 32768
  int o = i & (OO - 1);
  int k = i >> 7;
  Wt[(size_t)o * (2 * FF) + k] = (_Float16)W[i];
}

// ---- fused: in-block sort + 2x-unrolled register pull + MFMA + tanh -------
#define LITERS ((SCAP + 511) / 512)  // 9
__global__ __launch_bounds__(512, 8) void pullsort_fused_kernel(
    const unsigned int* __restrict__ featb, const _Float16* __restrict__ Wt,
    const uintx2* __restrict__ recs, const unsigned int* __restrict__ bstart,
    float* __restrict__ out) {
  __shared__ __align__(16) unsigned char smem[SCAP * 8];  // 36 KB
  __shared__ unsigned int h[BROWS], st[BROWS], cur[BROWS];
  uintx2* buf = (uintx2*)smem;
  _Float16* G_h = (_Float16*)smem;  // aliased: 32*256*2B = 16KB
  const int tid = threadIdx.x;
  const int b = blockIdx.x;
  const unsigned int e0 = bstart[b];
  const unsigned int e1b = bstart[b + 1];
  const int len = (int)(e1b - e0);
  const bool fits = (len <= SCAP);

  if (tid < BROWS) h[tid] = 0;
  __syncthreads();

  uintx2 loc[LITERS];
  if (fits) {
#pragma unroll
    for (int it = 0; it < LITERS; ++it) {
      int i = tid + it * 512;
      if (i < len) {
        uintx2 r = __builtin_nontemporal_load(&recs[e0 + i]);
        loc[it] = r;
        atomicAdd(&h[(r.x >> 17) & 31u], 1u);
      }
    }
  }
  __syncthreads();
  if (tid == 0) {
    unsigned int run = 0;
#pragma unroll
    for (int j = 0; j < BROWS; ++j) {
      st[j] = run;
      cur[j] = run;
      run += h[j];
    }
  }
  __syncthreads();
  if (fits) {
#pragma unroll
    for (int it = 0; it < LITERS; ++it) {
      int i = tid + it * 512;
      if (i < len) {
        uintx2 r = loc[it];
        unsigned int pos = atomicAdd(&cur[(r.x >> 17) & 31u], 1u);
        buf[pos] = r;
      }
    }
  }
  __syncthreads();

  // pull phase: row nl = tid>>4, feature chunk q = tid&15 (elems 8q..8q+7)
  const int nl = tid >> 4;
  const int q = tid & 15;
  float a0[8], a1[8], b0a[8], b1a[8];
#pragma unroll
  for (int k = 0; k < 8; ++k) {
    a0[k] = 0.f;
    a1[k] = 0.f;
    b0a[k] = 0.f;
    b1a[k] = 0.f;
  }

  if (fits) {
    const unsigned int rbeg = st[nl];
    const unsigned int rend = rbeg + h[nl];
    unsigned int e = rbeg;
    // 2x unrolled: two independent gathers in flight per iteration
    for (; e + 2 <= rend; e += 2) {
      uintx2 r1 = buf[e];
      uintx2 r2 = buf[e + 1];
      uint4 x1 = *reinterpret_cast<const uint4*>(
          &featb[((r1.x & 0x1FFFFu) << 6) + (q << 2)]);
      uint4 x2 = *reinterpret_cast<const uint4*>(
          &featb[((r2.x & 0x1FFFFu) << 6) + (q << 2)]);
      float2 v1 = h2_to_f2(r1.y);
      float2 v2 = h2_to_f2(r2.y);
      const __half2* hp1 = reinterpret_cast<const __half2*>(&x1);
      const __half2* hp2 = reinterpret_cast<const __half2*>(&x2);
#pragma unroll
      for (int m = 0; m < 4; ++m) {
        float2 f1 = __half22float2(hp1[m]);
        float2 f2 = __half22float2(hp2[m]);
        a0[2 * m] += v1.x * f1.x;
        a0[2 * m + 1] += v1.x * f1.y;
        a1[2 * m] += v1.y * f1.x;
        a1[2 * m + 1] += v1.y * f1.y;
        b0a[2 * m] += v2.x * f2.x;
        b0a[2 * m + 1] += v2.x * f2.y;
        b1a[2 * m] += v2.y * f2.x;
        b1a[2 * m + 1] += v2.y * f2.y;
      }
    }
    if (e < rend) {
      uintx2 r1 = buf[e];
      uint4 x1 = *reinterpret_cast<const uint4*>(
          &featb[((r1.x & 0x1FFFFu) << 6) + (q << 2)]);
      float2 v1 = h2_to_f2(r1.y);
      const __half2* hp1 = reinterpret_cast<const __half2*>(&x1);
#pragma unroll
      for (int m = 0; m < 4; ++m) {
        float2 f1 = __half22float2(hp1[m]);
        a0[2 * m] += v1.x * f1.x;
        a0[2 * m + 1] += v1.x * f1.y;
        a1[2 * m] += v1.y * f1.x;
        a1[2 * m + 1] += v1.y * f1.y;
      }
    }
#pragma unroll
    for (int k = 0; k < 8; ++k) {
      a0[k] += b0a[k];
      a1[k] += b1a[k];
    }
  } else {
    // overflow fallback (statistically never): filter-scan global records
    for (unsigned int e = e0; e < e1b; ++e) {
      uintx2 rec = recs[e];
      if ((int)((rec.x >> 17) & 31u) == nl) {
        unsigned int c = rec.x & 0x1FFFFu;
        float2 vv = h2_to_f2(rec.y);
        uint4 xv = *reinterpret_cast<const uint4*>(&featb[(c << 6) + (q << 2)]);
        const __half2* hp = reinterpret_cast<const __half2*>(&xv);
#pragma unroll
        for (int m = 0; m < 4; ++m) {
          float2 f = __half22float2(hp[m]);
          a0[2 * m] += vv.x * f.x;
          a0[2 * m + 1] += vv.x * f.y;
          a1[2 * m] += vv.y * f.x;
          a1[2 * m + 1] += vv.y * f.y;
        }
      }
    }
  }
  __syncthreads();  // all buf reads done before G_h overwrites it (alias)

  // write fp16 G_h[32][256] with XOR-swizzled 16B granules
  {
    f16x8 h0, h1;
#pragma unroll
    for (int k = 0; k < 8; ++k) {
      h0[k] = (_Float16)a0[k];
      h1[k] = (_Float16)a1[k];
    }
    int g0 = q ^ (nl & 7);          // granule of a0 (elems q*8..q*8+7)
    int g1 = (16 + q) ^ (nl & 7);   // granule of a1 (elems 128+q*8..)
    *reinterpret_cast<f16x8*>(&G_h[nl * 256 + g0 * 8]) = h0;
    *reinterpret_cast<f16x8*>(&G_h[nl * 256 + g1 * 8]) = h1;
  }
  __syncthreads();

  // MFMA epilogue: out[b*32+row][o] = tanh( G_h[row][:] . Wt[o][:] )
  const int wv = tid >> 6;
  const int lane = tid & 63;
  const int m = wv & 1;
  const int n0 = wv >> 1;
  const int arow = m * 16 + (lane & 15);
  const int gsel = lane >> 4;
  f32x4 acc0 = {0.f, 0.f, 0.f, 0.f};
  f32x4 acc1 = {0.f, 0.f, 0.f, 0.f};
#pragma unroll
  for (int kk = 0; kk < 8; ++kk) {
    int gr = kk * 4 + gsel;  // 16B granule index within row
    f16x8 af = *reinterpret_cast<const f16x8*>(
        &G_h[arow * 256 + (gr ^ (arow & 7)) * 8]);
    int kbase = kk * 32 + gsel * 8;
    f16x8 bb0 = *reinterpret_cast<const f16x8*>(
        &Wt[(size_t)(n0 * 16 + (lane & 15)) * 256 + kbase]);
    f16x8 bb1 = *reinterpret_cast<const f16x8*>(
        &Wt[(size_t)((n0 + 4) * 16 + (lane & 15)) * 256 + kbase]);
    acc0 = __builtin_amdgcn_mfma_f32_16x16x32_f16(af, bb0, acc0, 0, 0, 0);
    acc1 = __builtin_amdgcn_mfma_f32_16x16x32_f16(af, bb1, acc1, 0, 0, 0);
  }
  // C layout (m89-verified): col = lane&15, row = (lane>>4)*4 + reg
  {
    int crow = b * BROWS + m * 16 + (lane >> 4) * 4;
    int ccol = lane & 15;
#pragma unroll
    for (int r = 0; r < 4; ++r) {
      out[(size_t)(crow + r) * OO + n0 * 16 + ccol] = tanhf(acc0[r]);
      out[(size_t)(crow + r) * OO + (n0 + 4) * 16 + ccol] = tanhf(acc1[r]);
    }
  }
}

// ===========================================================================
// FALLBACK PATH (round-1, proven): used only if ws_size is too small
// ===========================================================================
__global__ void compute_V_kernel(const float* __restrict__ W,
                                 const float* __restrict__ Wc,
                                 float* __restrict__ V) {
  int i = blockIdx.x * blockDim.x + threadIdx.x;
  int s = i >> 14;
  int fo = i & 16383;
  V[i] = Wc[s * BBASES + 0] * W[fo] + Wc[s * BBASES + 1] * W[16384 + fo];
}

__global__ __launch_bounds__(256) void scatter_kernel(
    const float* __restrict__ feat, const int* __restrict__ rows,
    const int* __restrict__ cols, const float* __restrict__ vals,
    float* __restrict__ agg) {
  int t = blockIdx.x * blockDim.x + threadIdx.x;
  int e = t >> 5;
  int qq = t & 31;
  if (e >= EE) return;
  int r = rows[e];
  int c = cols[e];
  float v = vals[e];
  const float4 x = *reinterpret_cast<const float4*>(&feat[(size_t)c * FF + qq * 4]);
  float* dst = &agg[(size_t)r * FF + qq * 4];
  unsafeAtomicAdd(dst + 0, v * x.x);
  unsafeAtomicAdd(dst + 1, v * x.y);
  unsafeAtomicAdd(dst + 2, v * x.z);
  unsafeAtomicAdd(dst + 3, v * x.w);
}

__global__ __launch_bounds__(256) void gemm_acc_kernel(
    const float* __restrict__ A, const float* __restrict__ Bv,
    float* __restrict__ C) {
  __shared__ float As[16][64];
  __shared__ float Bs[16][128];
  const int tid = threadIdx.x;
  const int bm0 = blockIdx.x * 64;
  const int tx = tid & 31;
  const int ty = tid >> 5;
  float acc[8][4];
#pragma unroll
  for (int r = 0; r < 8; ++r)
#pragma unroll
    for (int c = 0; c < 4; ++c) acc[r][c] = 0.0f;
  const int ar = tid >> 2;
  const int akq = tid & 3;
  for (int k0 = 0; k0 < FF; k0 += 16) {
    {
      int row = bm0 + ar;
      float4 av = make_float4(0.f, 0.f, 0.f, 0.f);
      if (row < NN)
        av = *reinterpret_cast<const float4*>(&A[(size_t)row * FF + k0 + akq * 4]);
      As[akq * 4 + 0][ar] = av.x;
      As[akq * 4 + 1][ar] = av.y;
      As[akq * 4 + 2][ar] = av.z;
      As[akq * 4 + 3][ar] = av.w;
    }
#pragma unroll
    for (int i = 0; i < 2; ++i) {
      int v = tid + i * 256;
      int kk = v >> 5;
      int cq = v & 31;
      *reinterpret_cast<float4*>(&Bs[kk][cq * 4]) =
          *reinterpret_cast<const float4*>(&Bv[(k0 + kk) * OO + cq * 4]);
    }
    __syncthreads();
#pragma unroll
    for (int kk = 0; kk < 16; ++kk) {
      float4 b = *reinterpret_cast<const float4*>(&Bs[kk][tx * 4]);
#pragma unroll
      for (int r = 0; r < 8; ++r) {
        float a = As[kk][ty * 8 + r];
        acc[r][0] += a * b.x;
        acc[r][1] += a * b.y;
        acc[r][2] += a * b.z;
        acc[r][3] += a * b.w;
      }
    }
    __syncthreads();
  }
#pragma unroll
  for (int r = 0; r < 8; ++r) {
    int row = bm0 + ty * 8 + r;
    if (row < NN) {
      float4* cp = reinterpret_cast<float4*>(&C[(size_t)row * OO + tx * 4]);
      float4 c = *cp;
      c.x += acc[r][0];
      c.y += acc[r][1];
      c.z += acc[r][2];
      c.w += acc[r][3];
      *cp = c;
    }
  }
}

__global__ __launch_bounds__(256) void tanh_kernel(float* __restrict__ out) {
  int i = blockIdx.x * blockDim.x + threadIdx.x;
  float4* p = reinterpret_cast<float4*>(out) + i;
  float4 v = *p;
  v.x = tanhf(v.x);
  v.y = tanhf(v.y);
  v.z = tanhf(v.z);
  v.w = tanhf(v.w);
  *p = v;
}

// ===========================================================================
extern "C" void kernel_launch(void* const* d_in, const int* in_sizes, int n_in,
                              void* d_out, int out_size, void* d_ws,
                              size_t ws_size, hipStream_t stream) {
  const float* feat = (const float*)d_in[0];   // [N, F]
  const float* W = (const float*)d_in[1];      // [B, F, O]
  const float* Wc = (const float*)d_in[2];     // [S, B]
  const int* erows = (const int*)d_in[3];      // [S, E]
  const int* ecols = (const int*)d_in[4];      // [S, E]
  const float* evals = (const float*)d_in[5];  // [S, E]
  float* out = (float*)d_out;                  // [N, O] f32

  unsigned char* ws = (unsigned char*)d_ws;
  size_t off = 0;
  unsigned int* bhist = (unsigned int*)(ws + off);
  off += (((size_t)NBUK * 4) + 255) & ~(size_t)255;
  unsigned int* bstart = (unsigned int*)(ws + off);
  off += (((size_t)(NBUK + 1) * 4) + 255) & ~(size_t)255;
  unsigned int* fcur = (unsigned int*)(ws + off);
  off += (((size_t)NBUK * 4) + 255) & ~(size_t)255;
  unsigned int* ccur = (unsigned int*)(ws + off);
  off += (((size_t)NCOARSE * 4) + 255) & ~(size_t)255;
  uintx2* recsA = (uintx2*)(ws + off);  // 102.4MB
  off += (size_t)TOTE * 8;
  unsigned int* featb = (unsigned int*)(ws + off);  // 25.6MB
  off += (size_t)NN * FF * 2;
  _Float16* Wt = (_Float16*)(ws + off);  // 64KB, [128][256]
  size_t needB = off + (size_t)2 * FF * OO * 2;
  uintx2* recsB = (uintx2*)(ws + needB);  // +102.4MB (tier A only)
  size_t needA = needB + (size_t)TOTE * 8;

  if (ws_size >= needB) {
    hipMemsetAsync(bhist, 0, (size_t)NBUK * 4, stream);
    histB_kernel<<<RBLOCKS, 256, 0, stream>>>(erows, bhist);
    scanB_kernel<<<1, 256, 0, stream>>>(bhist, bstart, fcur, ccur);
    cast_kernel<<<(NN * FF / 2) / 256, 256, 0, stream>>>(feat, featb);
    castW_kernel<<<(2 * FF * OO) / 256, 256, 0, stream>>>(W, Wt);
    if (ws_size >= needA) {
      part1_kernel<<<RBLOCKS, 256, 0, stream>>>(erows, ecols, evals, Wc, ccur,
                                                recsA);
      part2_kernel<<<NCOARSE * P2PARTS, 256, 0, stream>>>(recsA, bstart, fcur,
                                                          recsB);
      pullsort_fused_kernel<<<NBUK, 512, 0, stream>>>(featb, Wt, recsB, bstart,
                                                      out);
    } else {
      partitionB_kernel<<<RBLOCKSB, 1024, 0, stream>>>(erows, ecols, evals, Wc,
                                                       fcur, recsA);
      pullsort_fused_kernel<<<NBUK, 512, 0, stream>>>(featb, Wt, recsA, bstart,
                                                      out);
    }
  } else {
    float* V = (float*)d_ws;
    float* agg = V + (size_t)SS * FF * OO;
    compute_V_kernel<<<(SS * FF * OO) / 256, 256, 0, stream>>>(W, Wc, V);
    hipMemsetAsync(out, 0, (size_t)NN * OO * sizeof(float), stream);
    for (int s = 0; s < SS; ++s) {
      hipMemsetAsync(agg, 0, (size_t)NN * FF * sizeof(float), stream);
      scatter_kernel<<<(EE * 32) / 256, 256, 0, stream>>>(
          feat, erows + (size_t)s * EE, ecols + (size_t)s * EE,
          evals + (size_t)s * EE, agg);
      gemm_acc_kernel<<<(NN + 63) / 64, 256, 0, stream>>>(
          agg, V + (size_t)s * FF * OO, out);
    }
    tanh_kernel<<<(NN * OO / 4) / 256, 256, 0, stream>>>(out);
  }
}

// Round 19
// 762.544 us; speedup vs baseline: 1.0489x; 1.0489x over previous
//
#include <hip/hip_runtime.h>
#include <hip/hip_bf16.h>
#include <hip/hip_fp16.h>

// Problem constants: N=100000, F=128, O=128, S=4, B=2, E=3200000
#define NN 100000
#define FF 128
#define OO 128
#define SS 4
#define BBASES 2
#define EE 3200000
#define TOTE (SS * EE)   // 12.8M edges total
#define BROWS 32         // rows per fine bucket
#define NBUK 3125        // 100000/32 exactly
#define NCOARSE 98       // row>>10 buckets (1024 rows each)
#define SCAP 4608        // LDS stage cap; lambda=4096, +8 sigma
#define HBLOCKS 512      // histB grid (512: low flush amplification)
#define R1BLOCKS 2048    // part1 grid (8 blocks/CU: occupancy fix, runs 512B)
#define P2PARTS 32

typedef unsigned int uintx2 __attribute__((ext_vector_type(2)));
typedef float floatx4 __attribute__((ext_vector_type(4)));
typedef _Float16 f16x8 __attribute__((ext_vector_type(8)));
typedef float f32x4 __attribute__((ext_vector_type(4)));

static __device__ __forceinline__ float2 h2_to_f2(unsigned int u) {
  __half2 h = *reinterpret_cast<__half2*>(&u);
  return __half22float2(h);
}

// ===========================================================================
// out[n] = tanh( G0[n] @ W0 + G1[n] @ W1 ),
//   G_b[n] = sum_{edges e->n} (val_e * Wc[s_e,b]) * feat[col_e]
// R19 = R17 (proven 718us) + unbundled prep fixes: part1 grid 2048 (was the
// 22%-occupancy kernel), P2PARTS 32 (1KB runs, no flush amp), histB stays
// 512 (R18's 2048 caused 6.4M flush atomics = the regression).
// Record: bits[16:0]=col, [21:17]=row&31, [26:22]=(row>>5)&31.
// rec.y = half2(val*w0, val*w1).
// ===========================================================================

// ---- fine-bucket histogram (LDS-staged) -----------------------------------
__global__ __launch_bounds__(256) void histB_kernel(
    const int* __restrict__ rows, unsigned int* __restrict__ bhist) {
  __shared__ unsigned int lh[NBUK];
  for (int i = threadIdx.x; i < NBUK; i += 256) lh[i] = 0;
  __syncthreads();
  const int stride = gridDim.x * 256;
  for (int i = blockIdx.x * 256 + threadIdx.x; i < TOTE; i += stride)
    atomicAdd(&lh[((unsigned)rows[i]) >> 5], 1u);
  __syncthreads();
  for (int i = threadIdx.x; i < NBUK; i += 256) {
    unsigned int c = lh[i];
    if (c) atomicAdd(&bhist[i], c);
  }
}

// ---- scan: fine bstart + fine cursors + coarse cursors --------------------
__global__ __launch_bounds__(256) void scanB_kernel(
    const unsigned int* __restrict__ bhist, unsigned int* __restrict__ bstart,
    unsigned int* __restrict__ fcur, unsigned int* __restrict__ ccur) {
  __shared__ unsigned int sums[256];
  const int C = (NBUK + 255) / 256;  // 14
  const int t = threadIdx.x;
  unsigned int s = 0;
  for (int j = 0; j < C; ++j) {
    int i = t * C + j;
    if (i < NBUK) s += bhist[i];
  }
  sums[t] = s;
  __syncthreads();
  for (int off = 1; off < 256; off <<= 1) {
    unsigned int v = (t >= off) ? sums[t - off] : 0u;
    __syncthreads();
    sums[t] += v;
    __syncthreads();
  }
  unsigned int base = (t == 0) ? 0u : sums[t - 1];
  for (int j = 0; j < C; ++j) {
    int i = t * C + j;
    if (i < NBUK) {
      unsigned int h = bhist[i];
      bstart[i] = base;
      fcur[i] = base;
      base += h;
    }
  }
  if (t == 255) bstart[NBUK] = base;  // == TOTE
  __syncthreads();
  if (t < NCOARSE) ccur[t] = bstart[t * 32];
}

// ---- P1: coarse partition (98 buckets), Wc fold, fine bits in record ------
__global__ __launch_bounds__(256) void part1_kernel(
    const int* __restrict__ rows, const int* __restrict__ cols,
    const float* __restrict__ vals, const float* __restrict__ Wc,
    unsigned int* __restrict__ ccur, uintx2* __restrict__ recsA) {
  __shared__ unsigned int lcnt[NCOARSE];
  __shared__ unsigned int lbase[NCOARSE];
  const float c00 = Wc[0], c01 = Wc[1], c10 = Wc[2], c11 = Wc[3];
  const float c20 = Wc[4], c21 = Wc[5], c30 = Wc[6], c31 = Wc[7];
  const int C = (TOTE + R1BLOCKS - 1) / R1BLOCKS;  // 6250
  const int start = blockIdx.x * C;
  const int end = min(start + C, TOTE);
  const int tid = threadIdx.x;
  if (tid < NCOARSE) lcnt[tid] = 0;
  __syncthreads();
  for (int i = start + tid; i < end; i += 256)
    atomicAdd(&lcnt[((unsigned)rows[i]) >> 10], 1u);
  __syncthreads();
  if (tid < NCOARSE) {
    unsigned int c = lcnt[tid];
    lbase[tid] = c ? atomicAdd(&ccur[tid], c) : 0u;
    lcnt[tid] = 0;
  }
  __syncthreads();
  for (int i = start + tid; i < end; i += 256) {
    unsigned int r = (unsigned)rows[i];
    int bk = r >> 10;
    unsigned int p = lbase[bk] + atomicAdd(&lcnt[bk], 1u);
    unsigned int s = (unsigned)(i / EE);
    float val = vals[i];
    float w0 = (s == 0) ? c00 : (s == 1) ? c10 : (s == 2) ? c20 : c30;
    float w1 = (s == 0) ? c01 : (s == 1) ? c11 : (s == 2) ? c21 : c31;
    __half2 hv = __floats2half2_rn(val * w0, val * w1);
    uintx2 rec;
    rec.x = ((unsigned)cols[i]) | ((r & 31u) << 17) | (((r >> 5) & 31u) << 22);
    rec.y = *reinterpret_cast<unsigned int*>(&hv);
    recsA[p] = rec;  // CACHED: L2 write-combines the 8B scatter
  }
}

// ---- P2: fine partition within each coarse region -------------------------
__global__ __launch_bounds__(256) void part2_kernel(
    const uintx2* __restrict__ recsA, const unsigned int* __restrict__ bstart,
    unsigned int* __restrict__ fcur, uintx2* __restrict__ recsB) {
  __shared__ unsigned int lcnt[32];
  __shared__ unsigned int lbase[32];
  const int c = blockIdx.x / P2PARTS;   // coarse bucket
  const int p = blockIdx.x % P2PARTS;
  const int f0 = c * 32;
  const int f1 = min(f0 + 32, NBUK);
  const unsigned int beg = bstart[f0];
  const unsigned int endc = bstart[f1];
  const unsigned int len = endc - beg;
  const unsigned int chunk = (len + P2PARTS - 1) / P2PARTS;
  const unsigned int s0 = beg + (unsigned)p * chunk;
  const unsigned int s1 = min(s0 + chunk, endc);
  const int tid = threadIdx.x;
  if (tid < 32) lcnt[tid] = 0;
  __syncthreads();
  for (unsigned int i = s0 + tid; i < s1; i += 256)
    atomicAdd(&lcnt[(recsA[i].x >> 22) & 31u], 1u);
  __syncthreads();
  if (tid < 32) {
    unsigned int cnt = lcnt[tid];
    lbase[tid] = (cnt && f0 + tid < NBUK) ? atomicAdd(&fcur[f0 + tid], cnt) : 0u;
    lcnt[tid] = 0;
  }
  __syncthreads();
  for (unsigned int i = s0 + tid; i < s1; i += 256) {
    uintx2 r = recsA[i];  // L2-hot second read
    unsigned int j = (r.x >> 22) & 31u;
    unsigned int pos = lbase[j] + atomicAdd(&lcnt[j], 1u);
    recsB[pos] = r;  // CACHED scatter
  }
}

// ---- Tier B: single-pass fine partition, 1024 threads ---------------------
#define RBLOCKSB 256
__global__ __launch_bounds__(1024) void partitionB_kernel(
    const int* __restrict__ rows, const int* __restrict__ cols,
    const float* __restrict__ vals, const float* __restrict__ Wc,
    unsigned int* __restrict__ fcur, uintx2* __restrict__ recs) {
  __shared__ unsigned int lcnt[NBUK];
  __shared__ unsigned int lbase[NBUK];
  const float c00 = Wc[0], c01 = Wc[1], c10 = Wc[2], c11 = Wc[3];
  const float c20 = Wc[4], c21 = Wc[5], c30 = Wc[6], c31 = Wc[7];
  const int C = (TOTE + RBLOCKSB - 1) / RBLOCKSB;  // 50000
  const int start = blockIdx.x * C;
  const int end = min(start + C, TOTE);
  const int tid = threadIdx.x;
  for (int i = tid; i < NBUK; i += 1024) lcnt[i] = 0;
  __syncthreads();
  for (int i = start + tid; i < end; i += 1024)
    atomicAdd(&lcnt[((unsigned)rows[i]) >> 5], 1u);
  __syncthreads();
  for (int i = tid; i < NBUK; i += 1024) {
    unsigned int c = lcnt[i];
    if (c) lbase[i] = atomicAdd(&fcur[i], c);
    lcnt[i] = 0;
  }
  __syncthreads();
  for (int i = start + tid; i < end; i += 1024) {
    unsigned int r = (unsigned)rows[i];
    int bk = r >> 5;
    unsigned int p = lbase[bk] + atomicAdd(&lcnt[bk], 1u);
    unsigned int s = (unsigned)(i / EE);
    float val = vals[i];
    float w0 = (s == 0) ? c00 : (s == 1) ? c10 : (s == 2) ? c20 : c30;
    float w1 = (s == 0) ? c01 : (s == 1) ? c11 : (s == 2) ? c21 : c31;
    __half2 hv = __floats2half2_rn(val * w0, val * w1);
    uintx2 rec;
    rec.x = ((unsigned)cols[i]) | ((r & 31u) << 17) | (((r >> 5) & 31u) << 22);
    rec.y = *reinterpret_cast<unsigned int*>(&hv);
    recs[p] = rec;  // CACHED scatter
  }
}

// ---- fp16 cast of feat: fb[i] packs elements 2i,2i+1 as half2 (RNE) -------
__global__ __launch_bounds__(256) void cast_kernel(const float* __restrict__ f,
                                                   unsigned int* __restrict__ fb) {
  int i = blockIdx.x * 256 + threadIdx.x;  // over N*F/2 = 6.4M pairs
  float2 a = reinterpret_cast<const float2*>(f)[i];
  __half2 h = __floats2half2_rn(a.x, a.y);
  fb[i] = *reinterpret_cast<unsigned int*>(&h);
}

// ---- fp16 transpose of W: Wt[o][k] = Wcat[k][o], [128][256] ---------------
__global__ __launch_bounds__(256) void castW_kernel(const float* __restrict__ W,
                                                    _Float16* __restrict__ Wt) {
  int i = blockIdx.x * 256 + threadIdx.x;  // over 2*FF*OO = 32768
  int o = i & (OO - 1);
  int k = i >> 7;
  Wt[(size_t)o * (2 * FF) + k] = (_Float16)W[i];
}

// ---- fused: in-block sort + register pull + MFMA + tanh (R17-proven) ------
#define LITERS ((SCAP + 511) / 512)  // 9
__global__ __launch_bounds__(512, 8) void pullsort_fused_kernel(
    const unsigned int* __restrict__ featb, const _Float16* __restrict__ Wt,
    const uintx2* __restrict__ recs, const unsigned int* __restrict__ bstart,
    float* __restrict__ out) {
  __shared__ __align__(16) unsigned char smem[SCAP * 8];  // 36 KB
  __shared__ unsigned int h[BROWS], st[BROWS], cur[BROWS];
  uintx2* buf = (uintx2*)smem;
  _Float16* G_h = (_Float16*)smem;  // aliased: 32*256*2B = 16KB
  const int tid = threadIdx.x;
  const int b = blockIdx.x;
  const unsigned int e0 = bstart[b];
  const unsigned int e1b = bstart[b + 1];
  const int len = (int)(e1b - e0);
  const bool fits = (len <= SCAP);

  if (tid < BROWS) h[tid] = 0;
  __syncthreads();

  uintx2 loc[LITERS];
  if (fits) {
#pragma unroll
    for (int it = 0; it < LITERS; ++it) {
      int i = tid + it * 512;
      if (i < len) {
        uintx2 r = __builtin_nontemporal_load(&recs[e0 + i]);
        loc[it] = r;
        atomicAdd(&h[(r.x >> 17) & 31u], 1u);
      }
    }
  }
  __syncthreads();
  if (tid == 0) {
    unsigned int run = 0;
#pragma unroll
    for (int j = 0; j < BROWS; ++j) {
      st[j] = run;
      cur[j] = run;
      run += h[j];
    }
  }
  __syncthreads();
  if (fits) {
#pragma unroll
    for (int it = 0; it < LITERS; ++it) {
      int i = tid + it * 512;
      if (i < len) {
        uintx2 r = loc[it];
        unsigned int pos = atomicAdd(&cur[(r.x >> 17) & 31u], 1u);
        buf[pos] = r;
      }
    }
  }
  __syncthreads();

  // pull phase: row nl = tid>>4, feature chunk q = tid&15 (elems 8q..8q+7)
  const int nl = tid >> 4;
  const int q = tid & 15;
  float a0[8], a1[8];
#pragma unroll
  for (int k = 0; k < 8; ++k) {
    a0[k] = 0.f;
    a1[k] = 0.f;
  }

  if (fits) {
    const unsigned int rbeg = st[nl];
    const unsigned int rend = rbeg + h[nl];
    for (unsigned int e = rbeg; e < rend; ++e) {
      uintx2 rec = buf[e];  // LDS broadcast across the 16 row-threads
      unsigned int c = rec.x & 0x1FFFFu;
      float2 vv = h2_to_f2(rec.y);
      uint4 xv = *reinterpret_cast<const uint4*>(&featb[(c << 6) + (q << 2)]);
      const __half2* hp = reinterpret_cast<const __half2*>(&xv);
#pragma unroll
      for (int m = 0; m < 4; ++m) {
        float2 f = __half22float2(hp[m]);
        a0[2 * m] += vv.x * f.x;
        a0[2 * m + 1] += vv.x * f.y;
        a1[2 * m] += vv.y * f.x;
        a1[2 * m + 1] += vv.y * f.y;
      }
    }
  } else {
    // overflow fallback (statistically never): filter-scan global records
    for (unsigned int e = e0; e < e1b; ++e) {
      uintx2 rec = recs[e];
      if ((int)((rec.x >> 17) & 31u) == nl) {
        unsigned int c = rec.x & 0x1FFFFu;
        float2 vv = h2_to_f2(rec.y);
        uint4 xv = *reinterpret_cast<const uint4*>(&featb[(c << 6) + (q << 2)]);
        const __half2* hp = reinterpret_cast<const __half2*>(&xv);
#pragma unroll
        for (int m = 0; m < 4; ++m) {
          float2 f = __half22float2(hp[m]);
          a0[2 * m] += vv.x * f.x;
          a0[2 * m + 1] += vv.x * f.y;
          a1[2 * m] += vv.y * f.x;
          a1[2 * m + 1] += vv.y * f.y;
        }
      }
    }
  }
  __syncthreads();  // all buf reads done before G_h overwrites it (alias)

  // write fp16 G_h[32][256] with XOR-swizzled 16B granules
  {
    f16x8 h0, h1;
#pragma unroll
    for (int k = 0; k < 8; ++k) {
      h0[k] = (_Float16)a0[k];
      h1[k] = (_Float16)a1[k];
    }
    int g0 = q ^ (nl & 7);          // granule of a0 (elems q*8..q*8+7)
    int g1 = (16 + q) ^ (nl & 7);   // granule of a1 (elems 128+q*8..)
    *reinterpret_cast<f16x8*>(&G_h[nl * 256 + g0 * 8]) = h0;
    *reinterpret_cast<f16x8*>(&G_h[nl * 256 + g1 * 8]) = h1;
  }
  __syncthreads();

  // MFMA epilogue: out[b*32+row][o] = tanh( G_h[row][:] . Wt[o][:] )
  const int wv = tid >> 6;
  const int lane = tid & 63;
  const int m = wv & 1;
  const int n0 = wv >> 1;
  const int arow = m * 16 + (lane & 15);
  const int gsel = lane >> 4;
  f32x4 acc0 = {0.f, 0.f, 0.f, 0.f};
  f32x4 acc1 = {0.f, 0.f, 0.f, 0.f};
#pragma unroll
  for (int kk = 0; kk < 8; ++kk) {
    int gr = kk * 4 + gsel;  // 16B granule index within row
    f16x8 af = *reinterpret_cast<const f16x8*>(
        &G_h[arow * 256 + (gr ^ (arow & 7)) * 8]);
    int kbase = kk * 32 + gsel * 8;
    f16x8 bb0 = *reinterpret_cast<const f16x8*>(
        &Wt[(size_t)(n0 * 16 + (lane & 15)) * 256 + kbase]);
    f16x8 bb1 = *reinterpret_cast<const f16x8*>(
        &Wt[(size_t)((n0 + 4) * 16 + (lane & 15)) * 256 + kbase]);
    acc0 = __builtin_amdgcn_mfma_f32_16x16x32_f16(af, bb0, acc0, 0, 0, 0);
    acc1 = __builtin_amdgcn_mfma_f32_16x16x32_f16(af, bb1, acc1, 0, 0, 0);
  }
  // C layout (m89-verified): col = lane&15, row = (lane>>4)*4 + reg
  {
    int crow = b * BROWS + m * 16 + (lane >> 4) * 4;
    int ccol = lane & 15;
#pragma unroll
    for (int r = 0; r < 4; ++r) {
      out[(size_t)(crow + r) * OO + n0 * 16 + ccol] = tanhf(acc0[r]);
      out[(size_t)(crow + r) * OO + (n0 + 4) * 16 + ccol] = tanhf(acc1[r]);
    }
  }
}

// ===========================================================================
// FALLBACK PATH (round-1, proven): used only if ws_size is too small
// ===========================================================================
__global__ void compute_V_kernel(const float* __restrict__ W,
                                 const float* __restrict__ Wc,
                                 float* __restrict__ V) {
  int i = blockIdx.x * blockDim.x + threadIdx.x;
  int s = i >> 14;
  int fo = i & 16383;
  V[i] = Wc[s * BBASES + 0] * W[fo] + Wc[s * BBASES + 1] * W[16384 + fo];
}

__global__ __launch_bounds__(256) void scatter_kernel(
    const float* __restrict__ feat, const int* __restrict__ rows,
    const int* __restrict__ cols, const float* __restrict__ vals,
    float* __restrict__ agg) {
  int t = blockIdx.x * blockDim.x + threadIdx.x;
  int e = t >> 5;
  int qq = t & 31;
  if (e >= EE) return;
  int r = rows[e];
  int c = cols[e];
  float v = vals[e];
  const float4 x = *reinterpret_cast<const float4*>(&feat[(size_t)c * FF + qq * 4]);
  float* dst = &agg[(size_t)r * FF + qq * 4];
  unsafeAtomicAdd(dst + 0, v * x.x);
  unsafeAtomicAdd(dst + 1, v * x.y);
  unsafeAtomicAdd(dst + 2, v * x.z);
  unsafeAtomicAdd(dst + 3, v * x.w);
}

__global__ __launch_bounds__(256) void gemm_acc_kernel(
    const float* __restrict__ A, const float* __restrict__ Bv,
    float* __restrict__ C) {
  __shared__ float As[16][64];
  __shared__ float Bs[16][128];
  const int tid = threadIdx.x;
  const int bm0 = blockIdx.x * 64;
  const int tx = tid & 31;
  const int ty = tid >> 5;
  float acc[8][4];
#pragma unroll
  for (int r = 0; r < 8; ++r)
#pragma unroll
    for (int c = 0; c < 4; ++c) acc[r][c] = 0.0f;
  const int ar = tid >> 2;
  const int akq = tid & 3;
  for (int k0 = 0; k0 < FF; k0 += 16) {
    {
      int row = bm0 + ar;
      float4 av = make_float4(0.f, 0.f, 0.f, 0.f);
      if (row < NN)
        av = *reinterpret_cast<const float4*>(&A[(size_t)row * FF + k0 + akq * 4]);
      As[akq * 4 + 0][ar] = av.x;
      As[akq * 4 + 1][ar] = av.y;
      As[akq * 4 + 2][ar] = av.z;
      As[akq * 4 + 3][ar] = av.w;
    }
#pragma unroll
    for (int i = 0; i < 2; ++i) {
      int v = tid + i * 256;
      int kk = v >> 5;
      int cq = v & 31;
      *reinterpret_cast<float4*>(&Bs[kk][cq * 4]) =
          *reinterpret_cast<const float4*>(&Bv[(k0 + kk) * OO + cq * 4]);
    }
    __syncthreads();
#pragma unroll
    for (int kk = 0; kk < 16; ++kk) {
      float4 b = *reinterpret_cast<const float4*>(&Bs[kk][tx * 4]);
#pragma unroll
      for (int r = 0; r < 8; ++r) {
        float a = As[kk][ty * 8 + r];
        acc[r][0] += a * b.x;
        acc[r][1] += a * b.y;
        acc[r][2] += a * b.z;
        acc[r][3] += a * b.w;
      }
    }
    __syncthreads();
  }
#pragma unroll
  for (int r = 0; r < 8; ++r) {
    int row = bm0 + ty * 8 + r;
    if (row < NN) {
      float4* cp = reinterpret_cast<float4*>(&C[(size_t)row * OO + tx * 4]);
      float4 c = *cp;
      c.x += acc[r][0];
      c.y += acc[r][1];
      c.z += acc[r][2];
      c.w += acc[r][3];
      *cp = c;
    }
  }
}

__global__ __launch_bounds__(256) void tanh_kernel(float* __restrict__ out) {
  int i = blockIdx.x * blockDim.x + threadIdx.x;
  float4* p = reinterpret_cast<float4*>(out) + i;
  float4 v = *p;
  v.x = tanhf(v.x);
  v.y = tanhf(v.y);
  v.z = tanhf(v.z);
  v.w = tanhf(v.w);
  *p = v;
}

// ===========================================================================
extern "C" void kernel_launch(void* const* d_in, const int* in_sizes, int n_in,
                              void* d_out, int out_size, void* d_ws,
                              size_t ws_size, hipStream_t stream) {
  const float* feat = (const float*)d_in[0];   // [N, F]
  const float* W = (const float*)d_in[1];      // [B, F, O]
  const float* Wc = (const float*)d_in[2];     // [S, B]
  const int* erows = (const int*)d_in[3];      // [S, E]
  const int* ecols = (const int*)d_in[4];      // [S, E]
  const float* evals = (const float*)d_in[5];  // [S, E]
  float* out = (float*)d_out;                  // [N, O] f32

  unsigned char* ws = (unsigned char*)d_ws;
  size_t off = 0;
  unsigned int* bhist = (unsigned int*)(ws + off);
  off += (((size_t)NBUK * 4) + 255) & ~(size_t)255;
  unsigned int* bstart = (unsigned int*)(ws + off);
  off += (((size_t)(NBUK + 1) * 4) + 255) & ~(size_t)255;
  unsigned int* fcur = (unsigned int*)(ws + off);
  off += (((size_t)NBUK * 4) + 255) & ~(size_t)255;
  unsigned int* ccur = (unsigned int*)(ws + off);
  off += (((size_t)NCOARSE * 4) + 255) & ~(size_t)255;
  uintx2* recsA = (uintx2*)(ws + off);  // 102.4MB
  off += (size_t)TOTE * 8;
  unsigned int* featb = (unsigned int*)(ws + off);  // 25.6MB
  off += (size_t)NN * FF * 2;
  _Float16* Wt = (_Float16*)(ws + off);  // 64KB, [128][256]
  size_t needB = off + (size_t)2 * FF * OO * 2;
  uintx2* recsB = (uintx2*)(ws + needB);  // +102.4MB (tier A only)
  size_t needA = needB + (size_t)TOTE * 8;

  if (ws_size >= needB) {
    hipMemsetAsync(bhist, 0, (size_t)NBUK * 4, stream);
    histB_kernel<<<HBLOCKS, 256, 0, stream>>>(erows, bhist);
    scanB_kernel<<<1, 256, 0, stream>>>(bhist, bstart, fcur, ccur);
    cast_kernel<<<(NN * FF / 2) / 256, 256, 0, stream>>>(feat, featb);
    castW_kernel<<<(2 * FF * OO) / 256, 256, 0, stream>>>(W, Wt);
    if (ws_size >= needA) {
      part1_kernel<<<R1BLOCKS, 256, 0, stream>>>(erows, ecols, evals, Wc, ccur,
                                                 recsA);
      part2_kernel<<<NCOARSE * P2PARTS, 256, 0, stream>>>(recsA, bstart, fcur,
                                                          recsB);
      pullsort_fused_kernel<<<NBUK, 512, 0, stream>>>(featb, Wt, recsB, bstart,
                                                      out);
    } else {
      partitionB_kernel<<<RBLOCKSB, 1024, 0, stream>>>(erows, ecols, evals, Wc,
                                                       fcur, recsA);
      pullsort_fused_kernel<<<NBUK, 512, 0, stream>>>(featb, Wt, recsA, bstart,
                                                      out);
    }
  } else {
    float* V = (float*)d_ws;
    float* agg = V + (size_t)SS * FF * OO;
    compute_V_kernel<<<(SS * FF * OO) / 256, 256, 0, stream>>>(W, Wc, V);
    hipMemsetAsync(out, 0, (size_t)NN * OO * sizeof(float), stream);
    for (int s = 0; s < SS; ++s) {
      hipMemsetAsync(agg, 0, (size_t)NN * FF * sizeof(float), stream);
      scatter_kernel<<<(EE * 32) / 256, 256, 0, stream>>>(
          feat, erows + (size_t)s * EE, ecols + (size_t)s * EE,
          evals + (size_t)s * EE, agg);
      gemm_acc_kernel<<<(NN + 63) / 64, 256, 0, stream>>>(
          agg, V + (size_t)s * FF * OO, out);
    }
    tanh_kernel<<<(NN * OO / 4) / 256, 256, 0, stream>>>(out);
  }
}

// Round 20
// 716.132 us; speedup vs baseline: 1.1169x; 1.0648x over previous
//
#include <hip/hip_runtime.h>
#include <hip/hip_bf16.h>
#include <hip/hip_fp16.h>

// Problem constants: N=100000, F=128, O=128, S=4, B=2, E=3200000
#define NN 100000
#define FF 128
#define OO 128
#define SS 4
#define BBASES 2
#define EE 3200000
#define TOTE (SS * EE)   // 12.8M edges total
#define BROWS 32         // rows per fine bucket
#define NBUK 3125        // 100000/32 exactly
#define NCOARSE 98       // row>>10 buckets (1024 rows each)
#define SCAP 4608        // LDS stage cap; lambda=4096, +8 sigma
#define RBLOCKS 512      // R20: restored to R17 (measured best). Scatter
#define P2PARTS 8        // write-front must fit L2: fewer resident blocks.

typedef unsigned int uintx2 __attribute__((ext_vector_type(2)));
typedef float floatx4 __attribute__((ext_vector_type(4)));
typedef _Float16 f16x8 __attribute__((ext_vector_type(8)));
typedef float f32x4 __attribute__((ext_vector_type(4)));

static __device__ __forceinline__ float2 h2_to_f2(unsigned int u) {
  __half2 h = *reinterpret_cast<__half2*>(&u);
  return __half22float2(h);
}

// ===========================================================================
// out[n] = tanh( G0[n] @ W0 + G1[n] @ W1 ),
//   G_b[n] = sum_{edges e->n} (val_e * Wc[s_e,b]) * feat[col_e]
// R20 = exact R17 restore (measured best, 718us). Lessons encoded:
//  - scattered sub-sector stores must be CACHED (nt -> 4x write amp, R15)
//  - scatter write-front must fit per-XCD L2 -> small grids for partition
//    kernels (R18/R19 regressions at 2048 blocks)
//  - pull loop ILP is compiler-canonicalized; structure changes are no-ops
// Record: bits[16:0]=col, [21:17]=row&31, [26:22]=(row>>5)&31.
// rec.y = half2(val*w0, val*w1).
// ===========================================================================

// ---- fine-bucket histogram (LDS-staged) -----------------------------------
__global__ __launch_bounds__(256) void histB_kernel(
    const int* __restrict__ rows, unsigned int* __restrict__ bhist) {
  __shared__ unsigned int lh[NBUK];
  for (int i = threadIdx.x; i < NBUK; i += 256) lh[i] = 0;
  __syncthreads();
  const int stride = gridDim.x * 256;
  for (int i = blockIdx.x * 256 + threadIdx.x; i < TOTE; i += stride)
    atomicAdd(&lh[((unsigned)rows[i]) >> 5], 1u);
  __syncthreads();
  for (int i = threadIdx.x; i < NBUK; i += 256) {
    unsigned int c = lh[i];
    if (c) atomicAdd(&bhist[i], c);
  }
}

// ---- scan: fine bstart + fine cursors + coarse cursors --------------------
__global__ __launch_bounds__(256) void scanB_kernel(
    const unsigned int* __restrict__ bhist, unsigned int* __restrict__ bstart,
    unsigned int* __restrict__ fcur, unsigned int* __restrict__ ccur) {
  __shared__ unsigned int sums[256];
  const int C = (NBUK + 255) / 256;  // 14
  const int t = threadIdx.x;
  unsigned int s = 0;
  for (int j = 0; j < C; ++j) {
    int i = t * C + j;
    if (i < NBUK) s += bhist[i];
  }
  sums[t] = s;
  __syncthreads();
  for (int off = 1; off < 256; off <<= 1) {
    unsigned int v = (t >= off) ? sums[t - off] : 0u;
    __syncthreads();
    sums[t] += v;
    __syncthreads();
  }
  unsigned int base = (t == 0) ? 0u : sums[t - 1];
  for (int j = 0; j < C; ++j) {
    int i = t * C + j;
    if (i < NBUK) {
      unsigned int h = bhist[i];
      bstart[i] = base;
      fcur[i] = base;
      base += h;
    }
  }
  if (t == 255) bstart[NBUK] = base;  // == TOTE
  __syncthreads();
  if (t < NCOARSE) ccur[t] = bstart[t * 32];
}

// ---- P1: coarse partition (98 buckets), Wc fold, fine bits in record ------
__global__ __launch_bounds__(256) void part1_kernel(
    const int* __restrict__ rows, const int* __restrict__ cols,
    const float* __restrict__ vals, const float* __restrict__ Wc,
    unsigned int* __restrict__ ccur, uintx2* __restrict__ recsA) {
  __shared__ unsigned int lcnt[NCOARSE];
  __shared__ unsigned int lbase[NCOARSE];
  const float c00 = Wc[0], c01 = Wc[1], c10 = Wc[2], c11 = Wc[3];
  const float c20 = Wc[4], c21 = Wc[5], c30 = Wc[6], c31 = Wc[7];
  const int C = (TOTE + RBLOCKS - 1) / RBLOCKS;  // 25000
  const int start = blockIdx.x * C;
  const int end = min(start + C, TOTE);
  const int tid = threadIdx.x;
  if (tid < NCOARSE) lcnt[tid] = 0;
  __syncthreads();
  for (int i = start + tid; i < end; i += 256)
    atomicAdd(&lcnt[((unsigned)rows[i]) >> 10], 1u);
  __syncthreads();
  if (tid < NCOARSE) {
    unsigned int c = lcnt[tid];
    lbase[tid] = c ? atomicAdd(&ccur[tid], c) : 0u;
    lcnt[tid] = 0;
  }
  __syncthreads();
  for (int i = start + tid; i < end; i += 256) {
    unsigned int r = (unsigned)rows[i];
    int bk = r >> 10;
    unsigned int p = lbase[bk] + atomicAdd(&lcnt[bk], 1u);
    unsigned int s = (unsigned)(i / EE);
    float val = vals[i];
    float w0 = (s == 0) ? c00 : (s == 1) ? c10 : (s == 2) ? c20 : c30;
    float w1 = (s == 0) ? c01 : (s == 1) ? c11 : (s == 2) ? c21 : c31;
    __half2 hv = __floats2half2_rn(val * w0, val * w1);
    uintx2 rec;
    rec.x = ((unsigned)cols[i]) | ((r & 31u) << 17) | (((r >> 5) & 31u) << 22);
    rec.y = *reinterpret_cast<unsigned int*>(&hv);
    recsA[p] = rec;  // CACHED: L2 write-combines the 8B scatter
  }
}

// ---- P2: fine partition within each coarse region -------------------------
__global__ __launch_bounds__(256) void part2_kernel(
    const uintx2* __restrict__ recsA, const unsigned int* __restrict__ bstart,
    unsigned int* __restrict__ fcur, uintx2* __restrict__ recsB) {
  __shared__ unsigned int lcnt[32];
  __shared__ unsigned int lbase[32];
  const int c = blockIdx.x / P2PARTS;   // coarse bucket
  const int p = blockIdx.x % P2PARTS;
  const int f0 = c * 32;
  const int f1 = min(f0 + 32, NBUK);
  const unsigned int beg = bstart[f0];
  const unsigned int endc = bstart[f1];
  const unsigned int len = endc - beg;
  const unsigned int chunk = (len + P2PARTS - 1) / P2PARTS;
  const unsigned int s0 = beg + (unsigned)p * chunk;
  const unsigned int s1 = min(s0 + chunk, endc);
  const int tid = threadIdx.x;
  if (tid < 32) lcnt[tid] = 0;
  __syncthreads();
  for (unsigned int i = s0 + tid; i < s1; i += 256)
    atomicAdd(&lcnt[(recsA[i].x >> 22) & 31u], 1u);
  __syncthreads();
  if (tid < 32) {
    unsigned int cnt = lcnt[tid];
    lbase[tid] = (cnt && f0 + tid < NBUK) ? atomicAdd(&fcur[f0 + tid], cnt) : 0u;
    lcnt[tid] = 0;
  }
  __syncthreads();
  for (unsigned int i = s0 + tid; i < s1; i += 256) {
    uintx2 r = recsA[i];  // L2-hot second read
    unsigned int j = (r.x >> 22) & 31u;
    unsigned int pos = lbase[j] + atomicAdd(&lcnt[j], 1u);
    recsB[pos] = r;  // CACHED scatter
  }
}

// ---- Tier B: single-pass fine partition, 1024 threads ---------------------
#define RBLOCKSB 256
__global__ __launch_bounds__(1024) void partitionB_kernel(
    const int* __restrict__ rows, const int* __restrict__ cols,
    const float* __restrict__ vals, const float* __restrict__ Wc,
    unsigned int* __restrict__ fcur, uintx2* __restrict__ recs) {
  __shared__ unsigned int lcnt[NBUK];
  __shared__ unsigned int lbase[NBUK];
  const float c00 = Wc[0], c01 = Wc[1], c10 = Wc[2], c11 = Wc[3];
  const float c20 = Wc[4], c21 = Wc[5], c30 = Wc[6], c31 = Wc[7];
  const int C = (TOTE + RBLOCKSB - 1) / RBLOCKSB;  // 50000
  const int start = blockIdx.x * C;
  const int end = min(start + C, TOTE);
  const int tid = threadIdx.x;
  for (int i = tid; i < NBUK; i += 1024) lcnt[i] = 0;
  __syncthreads();
  for (int i = start + tid; i < end; i += 1024)
    atomicAdd(&lcnt[((unsigned)rows[i]) >> 5], 1u);
  __syncthreads();
  for (int i = tid; i < NBUK; i += 1024) {
    unsigned int c = lcnt[i];
    if (c) lbase[i] = atomicAdd(&fcur[i], c);
    lcnt[i] = 0;
  }
  __syncthreads();
  for (int i = start + tid; i < end; i += 1024) {
    unsigned int r = (unsigned)rows[i];
    int bk = r >> 5;
    unsigned int p = lbase[bk] + atomicAdd(&lcnt[bk], 1u);
    unsigned int s = (unsigned)(i / EE);
    float val = vals[i];
    float w0 = (s == 0) ? c00 : (s == 1) ? c10 : (s == 2) ? c20 : c30;
    float w1 = (s == 0) ? c01 : (s == 1) ? c11 : (s == 2) ? c21 : c31;
    __half2 hv = __floats2half2_rn(val * w0, val * w1);
    uintx2 rec;
    rec.x = ((unsigned)cols[i]) | ((r & 31u) << 17) | (((r >> 5) & 31u) << 22);
    rec.y = *reinterpret_cast<unsigned int*>(&hv);
    recs[p] = rec;  // CACHED scatter
  }
}

// ---- fp16 cast of feat: fb[i] packs elements 2i,2i+1 as half2 (RNE) -------
__global__ __launch_bounds__(256) void cast_kernel(const float* __restrict__ f,
                                                   unsigned int* __restrict__ fb) {
  int i = blockIdx.x * 256 + threadIdx.x;  // over N*F/2 = 6.4M pairs
  float2 a = reinterpret_cast<const float2*>(f)[i];
  __half2 h = __floats2half2_rn(a.x, a.y);
  fb[i] = *reinterpret_cast<unsigned int*>(&h);
}

// ---- fp16 transpose of W: Wt[o][k] = Wcat[k][o], [128][256] ---------------
__global__ __launch_bounds__(256) void castW_kernel(const float* __restrict__ W,
                                                    _Float16* __restrict__ Wt) {
  int i = blockIdx.x * 256 + threadIdx.x;  // over 2*FF*OO = 32768
  int o = i & (OO - 1);
  int k = i >> 7;
  Wt[(size_t)o * (2 * FF) + k] = (_Float16)W[i];
}

// ---- fused: in-block sort + register pull + MFMA + tanh (R17-proven) ------
#define LITERS ((SCAP + 511) / 512)  // 9
__global__ __launch_bounds__(512, 8) void pullsort_fused_kernel(
    const unsigned int* __restrict__ featb, const _Float16* __restrict__ Wt,
    const uintx2* __restrict__ recs, const unsigned int* __restrict__ bstart,
    float* __restrict__ out) {
  __shared__ __align__(16) unsigned char smem[SCAP * 8];  // 36 KB
  __shared__ unsigned int h[BROWS], st[BROWS], cur[BROWS];
  uintx2* buf = (uintx2*)smem;
  _Float16* G_h = (_Float16*)smem;  // aliased: 32*256*2B = 16KB
  const int tid = threadIdx.x;
  const int b = blockIdx.x;
  const unsigned int e0 = bstart[b];
  const unsigned int e1b = bstart[b + 1];
  const int len = (int)(e1b - e0);
  const bool fits = (len <= SCAP);

  if (tid < BROWS) h[tid] = 0;
  __syncthreads();

  uintx2 loc[LITERS];
  if (fits) {
#pragma unroll
    for (int it = 0; it < LITERS; ++it) {
      int i = tid + it * 512;
      if (i < len) {
        uintx2 r = __builtin_nontemporal_load(&recs[e0 + i]);
        loc[it] = r;
        atomicAdd(&h[(r.x >> 17) & 31u], 1u);
      }
    }
  }
  __syncthreads();
  if (tid == 0) {
    unsigned int run = 0;
#pragma unroll
    for (int j = 0; j < BROWS; ++j) {
      st[j] = run;
      cur[j] = run;
      run += h[j];
    }
  }
  __syncthreads();
  if (fits) {
#pragma unroll
    for (int it = 0; it < LITERS; ++it) {
      int i = tid + it * 512;
      if (i < len) {
        uintx2 r = loc[it];
        unsigned int pos = atomicAdd(&cur[(r.x >> 17) & 31u], 1u);
        buf[pos] = r;
      }
    }
  }
  __syncthreads();

  // pull phase: row nl = tid>>4, feature chunk q = tid&15 (elems 8q..8q+7)
  const int nl = tid >> 4;
  const int q = tid & 15;
  float a0[8], a1[8];
#pragma unroll
  for (int k = 0; k < 8; ++k) {
    a0[k] = 0.f;
    a1[k] = 0.f;
  }

  if (fits) {
    const unsigned int rbeg = st[nl];
    const unsigned int rend = rbeg + h[nl];
    for (unsigned int e = rbeg; e < rend; ++e) {
      uintx2 rec = buf[e];  // LDS broadcast across the 16 row-threads
      unsigned int c = rec.x & 0x1FFFFu;
      float2 vv = h2_to_f2(rec.y);
      uint4 xv = *reinterpret_cast<const uint4*>(&featb[(c << 6) + (q << 2)]);
      const __half2* hp = reinterpret_cast<const __half2*>(&xv);
#pragma unroll
      for (int m = 0; m < 4; ++m) {
        float2 f = __half22float2(hp[m]);
        a0[2 * m] += vv.x * f.x;
        a0[2 * m + 1] += vv.x * f.y;
        a1[2 * m] += vv.y * f.x;
        a1[2 * m + 1] += vv.y * f.y;
      }
    }
  } else {
    // overflow fallback (statistically never): filter-scan global records
    for (unsigned int e = e0; e < e1b; ++e) {
      uintx2 rec = recs[e];
      if ((int)((rec.x >> 17) & 31u) == nl) {
        unsigned int c = rec.x & 0x1FFFFu;
        float2 vv = h2_to_f2(rec.y);
        uint4 xv = *reinterpret_cast<const uint4*>(&featb[(c << 6) + (q << 2)]);
        const __half2* hp = reinterpret_cast<const __half2*>(&xv);
#pragma unroll
        for (int m = 0; m < 4; ++m) {
          float2 f = __half22float2(hp[m]);
          a0[2 * m] += vv.x * f.x;
          a0[2 * m + 1] += vv.x * f.y;
          a1[2 * m] += vv.y * f.x;
          a1[2 * m + 1] += vv.y * f.y;
        }
      }
    }
  }
  __syncthreads();  // all buf reads done before G_h overwrites it (alias)

  // write fp16 G_h[32][256] with XOR-swizzled 16B granules
  {
    f16x8 h0, h1;
#pragma unroll
    for (int k = 0; k < 8; ++k) {
      h0[k] = (_Float16)a0[k];
      h1[k] = (_Float16)a1[k];
    }
    int g0 = q ^ (nl & 7);          // granule of a0 (elems q*8..q*8+7)
    int g1 = (16 + q) ^ (nl & 7);   // granule of a1 (elems 128+q*8..)
    *reinterpret_cast<f16x8*>(&G_h[nl * 256 + g0 * 8]) = h0;
    *reinterpret_cast<f16x8*>(&G_h[nl * 256 + g1 * 8]) = h1;
  }
  __syncthreads();

  // MFMA epilogue: out[b*32+row][o] = tanh( G_h[row][:] . Wt[o][:] )
  const int wv = tid >> 6;
  const int lane = tid & 63;
  const int m = wv & 1;
  const int n0 = wv >> 1;
  const int arow = m * 16 + (lane & 15);
  const int gsel = lane >> 4;
  f32x4 acc0 = {0.f, 0.f, 0.f, 0.f};
  f32x4 acc1 = {0.f, 0.f, 0.f, 0.f};
#pragma unroll
  for (int kk = 0; kk < 8; ++kk) {
    int gr = kk * 4 + gsel;  // 16B granule index within row
    f16x8 af = *reinterpret_cast<const f16x8*>(
        &G_h[arow * 256 + (gr ^ (arow & 7)) * 8]);
    int kbase = kk * 32 + gsel * 8;
    f16x8 bb0 = *reinterpret_cast<const f16x8*>(
        &Wt[(size_t)(n0 * 16 + (lane & 15)) * 256 + kbase]);
    f16x8 bb1 = *reinterpret_cast<const f16x8*>(
        &Wt[(size_t)((n0 + 4) * 16 + (lane & 15)) * 256 + kbase]);
    acc0 = __builtin_amdgcn_mfma_f32_16x16x32_f16(af, bb0, acc0, 0, 0, 0);
    acc1 = __builtin_amdgcn_mfma_f32_16x16x32_f16(af, bb1, acc1, 0, 0, 0);
  }
  // C layout (m89-verified): col = lane&15, row = (lane>>4)*4 + reg
  {
    int crow = b * BROWS + m * 16 + (lane >> 4) * 4;
    int ccol = lane & 15;
#pragma unroll
    for (int r = 0; r < 4; ++r) {
      out[(size_t)(crow + r) * OO + n0 * 16 + ccol] = tanhf(acc0[r]);
      out[(size_t)(crow + r) * OO + (n0 + 4) * 16 + ccol] = tanhf(acc1[r]);
    }
  }
}

// ===========================================================================
// FALLBACK PATH (round-1, proven): used only if ws_size is too small
// ===========================================================================
__global__ void compute_V_kernel(const float* __restrict__ W,
                                 const float* __restrict__ Wc,
                                 float* __restrict__ V) {
  int i = blockIdx.x * blockDim.x + threadIdx.x;
  int s = i >> 14;
  int fo = i & 16383;
  V[i] = Wc[s * BBASES + 0] * W[fo] + Wc[s * BBASES + 1] * W[16384 + fo];
}

__global__ __launch_bounds__(256) void scatter_kernel(
    const float* __restrict__ feat, const int* __restrict__ rows,
    const int* __restrict__ cols, const float* __restrict__ vals,
    float* __restrict__ agg) {
  int t = blockIdx.x * blockDim.x + threadIdx.x;
  int e = t >> 5;
  int qq = t & 31;
  if (e >= EE) return;
  int r = rows[e];
  int c = cols[e];
  float v = vals[e];
  const float4 x = *reinterpret_cast<const float4*>(&feat[(size_t)c * FF + qq * 4]);
  float* dst = &agg[(size_t)r * FF + qq * 4];
  unsafeAtomicAdd(dst + 0, v * x.x);
  unsafeAtomicAdd(dst + 1, v * x.y);
  unsafeAtomicAdd(dst + 2, v * x.z);
  unsafeAtomicAdd(dst + 3, v * x.w);
}

__global__ __launch_bounds__(256) void gemm_acc_kernel(
    const float* __restrict__ A, const float* __restrict__ Bv,
    float* __restrict__ C) {
  __shared__ float As[16][64];
  __shared__ float Bs[16][128];
  const int tid = threadIdx.x;
  const int bm0 = blockIdx.x * 64;
  const int tx = tid & 31;
  const int ty = tid >> 5;
  float acc[8][4];
#pragma unroll
  for (int r = 0; r < 8; ++r)
#pragma unroll
    for (int c = 0; c < 4; ++c) acc[r][c] = 0.0f;
  const int ar = tid >> 2;
  const int akq = tid & 3;
  for (int k0 = 0; k0 < FF; k0 += 16) {
    {
      int row = bm0 + ar;
      float4 av = make_float4(0.f, 0.f, 0.f, 0.f);
      if (row < NN)
        av = *reinterpret_cast<const float4*>(&A[(size_t)row * FF + k0 + akq * 4]);
      As[akq * 4 + 0][ar] = av.x;
      As[akq * 4 + 1][ar] = av.y;
      As[akq * 4 + 2][ar] = av.z;
      As[akq * 4 + 3][ar] = av.w;
    }
#pragma unroll
    for (int i = 0; i < 2; ++i) {
      int v = tid + i * 256;
      int kk = v >> 5;
      int cq = v & 31;
      *reinterpret_cast<float4*>(&Bs[kk][cq * 4]) =
          *reinterpret_cast<const float4*>(&Bv[(k0 + kk) * OO + cq * 4]);
    }
    __syncthreads();
#pragma unroll
    for (int kk = 0; kk < 16; ++kk) {
      float4 b = *reinterpret_cast<const float4*>(&Bs[kk][tx * 4]);
#pragma unroll
      for (int r = 0; r < 8; ++r) {
        float a = As[kk][ty * 8 + r];
        acc[r][0] += a * b.x;
        acc[r][1] += a * b.y;
        acc[r][2] += a * b.z;
        acc[r][3] += a * b.w;
      }
    }
    __syncthreads();
  }
#pragma unroll
  for (int r = 0; r < 8; ++r) {
    int row = bm0 + ty * 8 + r;
    if (row < NN) {
      float4* cp = reinterpret_cast<float4*>(&C[(size_t)row * OO + tx * 4]);
      float4 c = *cp;
      c.x += acc[r][0];
      c.y += acc[r][1];
      c.z += acc[r][2];
      c.w += acc[r][3];
      *cp = c;
    }
  }
}

__global__ __launch_bounds__(256) void tanh_kernel(float* __restrict__ out) {
  int i = blockIdx.x * blockDim.x + threadIdx.x;
  float4* p = reinterpret_cast<float4*>(out) + i;
  float4 v = *p;
  v.x = tanhf(v.x);
  v.y = tanhf(v.y);
  v.z = tanhf(v.z);
  v.w = tanhf(v.w);
  *p = v;
}

// ===========================================================================
extern "C" void kernel_launch(void* const* d_in, const int* in_sizes, int n_in,
                              void* d_out, int out_size, void* d_ws,
                              size_t ws_size, hipStream_t stream) {
  const float* feat = (const float*)d_in[0];   // [N, F]
  const float* W = (const float*)d_in[1];      // [B, F, O]
  const float* Wc = (const float*)d_in[2];     // [S, B]
  const int* erows = (const int*)d_in[3];      // [S, E]
  const int* ecols = (const int*)d_in[4];      // [S, E]
  const float* evals = (const float*)d_in[5];  // [S, E]
  float* out = (float*)d_out;                  // [N, O] f32

  unsigned char* ws = (unsigned char*)d_ws;
  size_t off = 0;
  unsigned int* bhist = (unsigned int*)(ws + off);
  off += (((size_t)NBUK * 4) + 255) & ~(size_t)255;
  unsigned int* bstart = (unsigned int*)(ws + off);
  off += (((size_t)(NBUK + 1) * 4) + 255) & ~(size_t)255;
  unsigned int* fcur = (unsigned int*)(ws + off);
  off += (((size_t)NBUK * 4) + 255) & ~(size_t)255;
  unsigned int* ccur = (unsigned int*)(ws + off);
  off += (((size_t)NCOARSE * 4) + 255) & ~(size_t)255;
  uintx2* recsA = (uintx2*)(ws + off);  // 102.4MB
  off += (size_t)TOTE * 8;
  unsigned int* featb = (unsigned int*)(ws + off);  // 25.6MB
  off += (size_t)NN * FF * 2;
  _Float16* Wt = (_Float16*)(ws + off);  // 64KB, [128][256]
  size_t needB = off + (size_t)2 * FF * OO * 2;
  uintx2* recsB = (uintx2*)(ws + needB);  // +102.4MB (tier A only)
  size_t needA = needB + (size_t)TOTE * 8;

  if (ws_size >= needB) {
    hipMemsetAsync(bhist, 0, (size_t)NBUK * 4, stream);
    histB_kernel<<<RBLOCKS, 256, 0, stream>>>(erows, bhist);
    scanB_kernel<<<1, 256, 0, stream>>>(bhist, bstart, fcur, ccur);
    cast_kernel<<<(NN * FF / 2) / 256, 256, 0, stream>>>(feat, featb);
    castW_kernel<<<(2 * FF * OO) / 256, 256, 0, stream>>>(W, Wt);
    if (ws_size >= needA) {
      part1_kernel<<<RBLOCKS, 256, 0, stream>>>(erows, ecols, evals, Wc, ccur,
                                                recsA);
      part2_kernel<<<NCOARSE * P2PARTS, 256, 0, stream>>>(recsA, bstart, fcur,
                                                          recsB);
      pullsort_fused_kernel<<<NBUK, 512, 0, stream>>>(featb, Wt, recsB, bstart,
                                                      out);
    } else {
      partitionB_kernel<<<RBLOCKSB, 1024, 0, stream>>>(erows, ecols, evals, Wc,
                                                       fcur, recsA);
      pullsort_fused_kernel<<<NBUK, 512, 0, stream>>>(featb, Wt, recsA, bstart,
                                                      out);
    }
  } else {
    float* V = (float*)d_ws;
    float* agg = V + (size_t)SS * FF * OO;
    compute_V_kernel<<<(SS * FF * OO) / 256, 256, 0, stream>>>(W, Wc, V);
    hipMemsetAsync(out, 0, (size_t)NN * OO * sizeof(float), stream);
    for (int s = 0; s < SS; ++s) {
      hipMemsetAsync(agg, 0, (size_t)NN * FF * sizeof(float), stream);
      scatter_kernel<<<(EE * 32) / 256, 256, 0, stream>>>(
          feat, erows + (size_t)s * EE, ecols + (size_t)s * EE,
          evals + (size_t)s * EE, agg);
      gemm_acc_kernel<<<(NN + 63) / 64, 256, 0, stream>>>(
          agg, V + (size_t)s * FF * OO, out);
    }
    tanh_kernel<<<(NN * OO / 4) / 256, 256, 0, stream>>>(out);
  }
}